// Round 6
// baseline (407.399 us; speedup 1.0000x reference)
//
#include <hip/hip_runtime.h>

// ---------------------------------------------------------------------------
// GCN 2-layer forward, MI355X.
//   CSR build via bucketed counting sort (unchanged from r3).
//   k_wsplit   : pre-split W -> bf16 hi/lo, transposed [n][k], XOR-swizzled
//   Per layer:
//     k_gemm_mfma : hs = bf16((X @ W) * dinv[row]) via split-bf16 MFMA,
//                   output in XCD-sliced layout hs[cg][node][16ch]
//     k_agg8      : channel-split gather; block's cg = blockIdx&7 pins each
//                   XCD (round-robin blk->XCD) to one 3.2MB slice -> L2-resident
// ---------------------------------------------------------------------------

#define NN 100000
#define NBKT 512
#define BKT_W 196
#define CHUNK 8192
#define CAP 6144

typedef __attribute__((ext_vector_type(8))) short bf16x8;
typedef __attribute__((ext_vector_type(4))) float f32x4;

__device__ __forceinline__ ushort f2bf(float f) {
  unsigned u = __float_as_uint(f);
  unsigned r = (u + 0x7fffu + ((u >> 16) & 1u)) >> 16;  // RNE
  return (ushort)r;
}
__device__ __forceinline__ float bf2f(ushort s) {
  return __uint_as_float(((unsigned)s) << 16);
}
__device__ __forceinline__ unsigned hipair(unsigned ue, unsigned uo) {
  return (uo & 0xffff0000u) | (ue >> 16);
}

// --- CSR build (unchanged) --------------------------------------------------

__global__ __launch_bounds__(512) void kb_hist(const int* __restrict__ dst,
                                               int* __restrict__ bcnt, int E) {
  __shared__ int h[NBKT];
  for (int i = threadIdx.x; i < NBKT; i += 512) h[i] = 0;
  __syncthreads();
  int base = blockIdx.x * CHUNK;
#pragma unroll 4
  for (int q = 0; q < CHUNK / 512; q++) {
    int e = base + threadIdx.x + q * 512;
    if (e < E) atomicAdd(&h[dst[e] / BKT_W], 1);
  }
  __syncthreads();
  for (int i = threadIdx.x; i < NBKT; i += 512)
    if (h[i]) atomicAdd(&bcnt[i], h[i]);
}

__global__ __launch_bounds__(512) void kb_scan(const int* __restrict__ bcnt,
                                               int* __restrict__ bbase,
                                               int* __restrict__ bcur,
                                               int* __restrict__ row_ptr,
                                               int N, int E) {
  __shared__ int s[NBKT];
  int t = threadIdx.x;
  int v = bcnt[t];
  s[t] = v;
  __syncthreads();
  for (int off = 1; off < NBKT; off <<= 1) {
    int x = (t >= off) ? s[t - off] : 0;
    __syncthreads();
    s[t] += x;
    __syncthreads();
  }
  int ex = s[t] - v;
  bbase[t] = ex;
  bcur[t] = ex;
  if (t == NBKT - 1) bbase[NBKT] = E;
  if (t == 0) row_ptr[N] = E;
}

__global__ __launch_bounds__(512) void kb_scatter(const int* __restrict__ src,
                                                  const int* __restrict__ dst,
                                                  int* __restrict__ bcur,
                                                  int2* __restrict__ pairs, int E) {
  __shared__ int h[NBKT];
  __shared__ int gb[NBKT];
  for (int i = threadIdx.x; i < NBKT; i += 512) h[i] = 0;
  __syncthreads();

  const int base = blockIdx.x * CHUNK;
  const int t = threadIdx.x;
  int rank[CHUNK / 512], bkt[CHUNK / 512], sv[CHUNK / 512], dv[CHUNK / 512];
#pragma unroll
  for (int q = 0; q < CHUNK / 512; q++) {
    int e = base + t + q * 512;
    if (e < E) {
      int d = dst[e];
      int b = d / BKT_W;
      bkt[q] = b;
      sv[q] = src[e];
      dv[q] = d;
      rank[q] = atomicAdd(&h[b], 1);
    } else {
      bkt[q] = -1;
    }
  }
  __syncthreads();
  for (int i = t; i < NBKT; i += 512) {
    int c = h[i];
    gb[i] = c ? atomicAdd(&bcur[i], c) : 0;
  }
  __syncthreads();
#pragma unroll
  for (int q = 0; q < CHUNK / 512; q++) {
    if (bkt[q] >= 0) pairs[(size_t)gb[bkt[q]] + rank[q]] = make_int2(sv[q], dv[q]);
  }
}

__global__ __launch_bounds__(512) void kb_sort(const int* __restrict__ bbase,
                                               const int2* __restrict__ pairs,
                                               int* __restrict__ csr_src,
                                               int* __restrict__ row_ptr,
                                               int N, int E) {
  __shared__ int cnt[256];
  __shared__ int sc[256];
  __shared__ int cur[256];
  __shared__ int stage[CAP];

  const int b = blockIdx.x;
  const int t = threadIdx.x;
  const int lo = bbase[b], hi = bbase[b + 1];
  const int n0 = b * BKT_W;
  int m = hi - lo;
  if (m > CAP) m = CAP;

  if (t < 256) cnt[t] = 0;
  __syncthreads();

  for (int i = t; i < m; i += 512) {
    int2 p = pairs[(size_t)lo + i];
    atomicAdd(&cnt[p.y - n0], 1);
  }
  __syncthreads();

  int v = 0;
  if (t < 256) {
    v = cnt[t];
    sc[t] = v;
  }
  __syncthreads();
  for (int off = 1; off < 256; off <<= 1) {
    int x = 0;
    if (t < 256 && t >= off) x = sc[t - off];
    __syncthreads();
    if (t < 256) sc[t] += x;
    __syncthreads();
  }
  if (t < 256) {
    int ex = sc[t] - v;
    cur[t] = ex;
    int node = n0 + t;
    if (t < BKT_W && node < N) row_ptr[node] = lo + ex;
  }
  __syncthreads();

  for (int i = t; i < m; i += 512) {
    int2 p = pairs[(size_t)lo + i];
    int pos = atomicAdd(&cur[p.y - n0], 1);
    stage[pos] = p.x;
  }
  __syncthreads();

  for (int i = t; i < m; i += 512) csr_src[(size_t)lo + i] = stage[i];
}

__global__ __launch_bounds__(256) void k_dinv(const int* __restrict__ row_ptr,
                                              float* __restrict__ dinv, int N) {
  int i = blockIdx.x * 256 + threadIdx.x;
  if (i < N) dinv[i] = rsqrtf((float)(row_ptr[i + 1] - row_ptr[i]) + 1.0f);
}

// --- W pre-split: W[128][128] f32 -> whi/wlo [n][k] bf16, XOR-swizzled ------
__global__ __launch_bounds__(256) void k_wsplit(const float* __restrict__ W,
                                                ushort* __restrict__ whi,
                                                ushort* __restrict__ wlo) {
  const int t = threadIdx.x;
#pragma unroll
  for (int it = 0; it < 16; ++it) {
    int f4 = it * 256 + t;          // 0..4095
    int k = f4 >> 5;
    int n4 = (f4 & 31) * 4;
    float4 v = *(const float4*)(W + (size_t)k * 128 + n4);
    float f[4] = {v.x, v.y, v.z, v.w};
#pragma unroll
    for (int q = 0; q < 4; ++q) {
      int n = n4 + q;
      unsigned u = __float_as_uint(f[q]);
      float lf = f[q] - __uint_as_float(u & 0xffff0000u);  // exact residual
      int bo = (n * 256 + k * 2) ^ ((n & 7) << 4);
      *(ushort*)((char*)whi + bo) = (ushort)(u >> 16);
      *(ushort*)((char*)wlo + bo) = (ushort)(__float_as_uint(lf) >> 16);
    }
  }
}

// --- MFMA GEMM: hs[cg][M][16](bf16) = ((X @ W) * dinv[row]) sliced ----------
__device__ __forceinline__ void cvt_row(const float* __restrict__ p,
                                        bf16x8* hi, bf16x8* lo) {
  float4 v0 = *(const float4*)p;
  float4 v1 = *(const float4*)(p + 4);
  float f[8] = {v0.x, v0.y, v0.z, v0.w, v1.x, v1.y, v1.z, v1.w};
  unsigned hw[4], lw[4];
#pragma unroll
  for (int i = 0; i < 4; ++i) {
    unsigned u0 = __float_as_uint(f[2 * i]);
    unsigned u1 = __float_as_uint(f[2 * i + 1]);
    float l0 = f[2 * i] - __uint_as_float(u0 & 0xffff0000u);
    float l1 = f[2 * i + 1] - __uint_as_float(u1 & 0xffff0000u);
    hw[i] = hipair(u0, u1);
    lw[i] = hipair(__float_as_uint(l0), __float_as_uint(l1));
  }
  uint4 H = make_uint4(hw[0], hw[1], hw[2], hw[3]);
  uint4 L = make_uint4(lw[0], lw[1], lw[2], lw[3]);
  *hi = __builtin_bit_cast(bf16x8, H);
  *lo = __builtin_bit_cast(bf16x8, L);
}

__global__ __launch_bounds__(256) void k_gemm_mfma(const float* __restrict__ X,
                                                   const ushort* __restrict__ whi,
                                                   const ushort* __restrict__ wlo,
                                                   const float* __restrict__ dinv,
                                                   ushort* __restrict__ hs, int M) {
  __shared__ ushort wt_hi[128 * 128];  // 32KB, pre-swizzled (linear copy)
  __shared__ ushort wt_lo[128 * 128];  // 32KB

  const int t = threadIdx.x;
#pragma unroll
  for (int it = 0; it < 8; ++it) {
    int o = (it * 256 + t) * 8;  // ushort index, 16B chunks
    *(uint4*)&wt_hi[o] = *(const uint4*)&whi[o];
    *(uint4*)&wt_lo[o] = *(const uint4*)&wlo[o];
  }
  __syncthreads();

  const int wv = t >> 6;
  const int lane = t & 63;
  const int r0 = blockIdx.x * 128 + wv * 32;
  const int la = lane & 15;
  const int kg = (lane >> 4) * 8;
  const int rowA = min(r0 + la, M - 1);
  const int rowB = min(r0 + 16 + la, M - 1);

  f32x4 acc[2][8];
#pragma unroll
  for (int rs = 0; rs < 2; ++rs)
#pragma unroll
    for (int ct = 0; ct < 8; ++ct) acc[rs][ct] = (f32x4)(0.f);

#pragma unroll
  for (int ks = 0; ks < 4; ++ks) {
    const int koff = ks * 32 + kg;
    bf16x8 ah0, al0, ah1, al1;
    cvt_row(X + (size_t)rowA * 128 + koff, &ah0, &al0);
    cvt_row(X + (size_t)rowB * 128 + koff, &ah1, &al1);
#pragma unroll
    for (int ct = 0; ct < 8; ++ct) {
      const int n = ct * 16 + la;
      const int bo = (n * 256 + koff * 2) ^ ((n & 7) << 4);
      bf16x8 bh = *(const bf16x8*)((const char*)wt_hi + bo);
      bf16x8 bl = *(const bf16x8*)((const char*)wt_lo + bo);
      acc[0][ct] = __builtin_amdgcn_mfma_f32_16x16x32_bf16(ah0, bh, acc[0][ct], 0, 0, 0);
      acc[0][ct] = __builtin_amdgcn_mfma_f32_16x16x32_bf16(ah0, bl, acc[0][ct], 0, 0, 0);
      acc[0][ct] = __builtin_amdgcn_mfma_f32_16x16x32_bf16(al0, bh, acc[0][ct], 0, 0, 0);
      acc[1][ct] = __builtin_amdgcn_mfma_f32_16x16x32_bf16(ah1, bh, acc[1][ct], 0, 0, 0);
      acc[1][ct] = __builtin_amdgcn_mfma_f32_16x16x32_bf16(ah1, bl, acc[1][ct], 0, 0, 0);
      acc[1][ct] = __builtin_amdgcn_mfma_f32_16x16x32_bf16(al1, bh, acc[1][ct], 0, 0, 0);
    }
  }

  // epilogue: C/D col = lane&15, row = (lane>>4)*4 + j.
  // slice layout: channel c = ct*16+la -> slice ct, offset la.
#pragma unroll
  for (int rs = 0; rs < 2; ++rs) {
#pragma unroll
    for (int j = 0; j < 4; ++j) {
      int r = r0 + rs * 16 + (lane >> 4) * 4 + j;
      if (r < M) {
        float sc = dinv[r];
#pragma unroll
        for (int ct = 0; ct < 8; ++ct)
          hs[(size_t)ct * M * 16 + (size_t)r * 16 + la] = f2bf(acc[rs][ct][j] * sc);
      }
    }
  }
}

// --- agg, channel-split: block handles 32 nodes x 16 channels (cg=bid&7) ----
// wave: 8 nodes x 8 lanes; lane owns 2 channels (ushort2).
__global__ __launch_bounds__(256) void k_agg8(const int* __restrict__ row_ptr,
                                              const int* __restrict__ csr_src,
                                              const float* __restrict__ dinv,
                                              const ushort* __restrict__ hs,
                                              const float* __restrict__ bias,
                                              float* __restrict__ out, int N) {
  const int cg = blockIdx.x & 7;
  const int ng = blockIdx.x >> 3;
  const int wv = threadIdx.x >> 6;
  const int lane = threadIdx.x & 63;
  const int sub = lane >> 3;  // node subgroup 0..7
  const int cl = lane & 7;    // ushort2 index within 16-ch slice
  const int node = ng * 32 + wv * 8 + sub;
  if (node >= N) return;

  const ushort2* hp = (const ushort2*)(hs + (size_t)cg * N * 16);  // [node][8]

  const int e0 = row_ptr[node];
  const int e1 = row_ptr[node + 1];

  float ax = 0.f, ay = 0.f;
  int e = e0;
  for (; e + 4 <= e1; e += 4) {
    int s0 = csr_src[e];
    int s1 = csr_src[e + 1];
    int s2 = csr_src[e + 2];
    int s3 = csr_src[e + 3];
    ushort2 v0 = hp[(size_t)s0 * 8 + cl];
    ushort2 v1 = hp[(size_t)s1 * 8 + cl];
    ushort2 v2 = hp[(size_t)s2 * 8 + cl];
    ushort2 v3 = hp[(size_t)s3 * 8 + cl];
    ax += bf2f(v0.x) + bf2f(v1.x) + bf2f(v2.x) + bf2f(v3.x);
    ay += bf2f(v0.y) + bf2f(v1.y) + bf2f(v2.y) + bf2f(v3.y);
  }
  for (; e < e1; ++e) {
    int s = csr_src[e];
    ushort2 v = hp[(size_t)s * 8 + cl];
    ax += bf2f(v.x);
    ay += bf2f(v.y);
  }
  {
    ushort2 v = hp[(size_t)node * 8 + cl];
    ax += bf2f(v.x);
    ay += bf2f(v.y);
  }
  float dv = dinv[node];
  float2 bv = ((const float2*)bias)[cg * 8 + cl];
  float2 o;
  o.x = fmaxf(fmaf(ax, dv, bv.x), 0.f);
  o.y = fmaxf(fmaf(ay, dv, bv.y), 0.f);
  ((float2*)out)[(size_t)node * 64 + cg * 8 + cl] = o;
}

// ---------------------------------------------------------------------------

extern "C" void kernel_launch(void* const* d_in, const int* in_sizes, int n_in,
                              void* d_out, int out_size, void* d_ws, size_t ws_size,
                              hipStream_t stream) {
  const float* x  = (const float*)d_in[0];
  const int*   ei = (const int*)d_in[1];
  const float* W1 = (const float*)d_in[2];
  const float* b1 = (const float*)d_in[3];
  const float* W2 = (const float*)d_in[4];
  const float* b2 = (const float*)d_in[5];
  float* out = (float*)d_out;

  const int N = NN;
  const int E = in_sizes[1] / 2;
  const int* src = ei;
  const int* dst = ei + E;

  char* w = (char*)d_ws;
  auto alloc = [&](size_t bytes) {
    char* p = w;
    w += (bytes + 255) & ~(size_t)255;
    return p;
  };
  float*  dinv    = (float*)alloc((size_t)N * 4);
  int*    row_ptr = (int*)alloc((size_t)(N + 1) * 4);
  int*    bcnt    = (int*)alloc(NBKT * 4);
  int*    bbase   = (int*)alloc((NBKT + 1) * 4);
  int*    bcur    = (int*)alloc(NBKT * 4);
  int*    csr_src = (int*)alloc((size_t)E * 4);
  int2*   pairs   = (int2*)alloc((size_t)E * 8);
  ushort* hs      = (ushort*)alloc((size_t)N * 128 * 2);
  ushort* w1hi    = (ushort*)alloc(128 * 128 * 2);
  ushort* w1lo    = (ushort*)alloc(128 * 128 * 2);
  ushort* w2hi    = (ushort*)alloc(128 * 128 * 2);
  ushort* w2lo    = (ushort*)alloc(128 * 128 * 2);

  const int EB = (E + CHUNK - 1) / CHUNK;

  hipMemsetAsync(bcnt, 0, NBKT * 4, stream);
  kb_hist<<<EB, 512, 0, stream>>>(dst, bcnt, E);
  kb_scan<<<1, 512, 0, stream>>>(bcnt, bbase, bcur, row_ptr, N, E);
  kb_scatter<<<EB, 512, 0, stream>>>(src, dst, bcur, pairs, E);
  kb_sort<<<NBKT, 512, 0, stream>>>(bbase, pairs, csr_src, row_ptr, N, E);
  k_dinv<<<(N + 255) / 256, 256, 0, stream>>>(row_ptr, dinv, N);
  k_wsplit<<<1, 256, 0, stream>>>(W1, w1hi, w1lo);
  k_wsplit<<<1, 256, 0, stream>>>(W2, w2hi, w2lo);

  const int GB = (N + 127) / 128;
  const int AB = ((N + 31) / 32) * 8;  // 3125 * 8 = 25000

  // layer 1
  k_gemm_mfma<<<GB, 256, 0, stream>>>(x, w1hi, w1lo, dinv, hs, N);
  k_agg8<<<AB, 256, 0, stream>>>(row_ptr, csr_src, dinv, hs, b1, out, N);
  // layer 2
  k_gemm_mfma<<<GB, 256, 0, stream>>>(out, w2hi, w2lo, dinv, hs, N);
  k_agg8<<<AB, 256, 0, stream>>>(row_ptr, csr_src, dinv, hs, b2, out, N);
}

// Round 9
// 353.171 us; speedup vs baseline: 1.1535x; 1.1535x over previous
//
#include <hip/hip_runtime.h>

// ---------------------------------------------------------------------------
// GCN 2-layer forward, MI355X.
//   CSR build via bucketed counting sort (r3).
//   k_wsplit    : pre-split W -> bf16 hi/lo, transposed [n][k], XOR-swizzled
//   Per layer:
//     k_gemm_mfma : hs[node][128](bf16) = bf16((X @ W) * dinv[row]), split-bf16
//     k_agg       : per-node wave gather; lane = uint2 (4ch), 32 lanes/row,
//                   2 edges per load instruction (half-wave per edge parity)
// ---------------------------------------------------------------------------

#define NN 100000
#define NBKT 512
#define BKT_W 196
#define CHUNK 8192
#define CAP 6144

typedef __attribute__((ext_vector_type(8))) short bf16x8;
typedef __attribute__((ext_vector_type(4))) float f32x4;

__device__ __forceinline__ ushort f2bf(float f) {
  unsigned u = __float_as_uint(f);
  unsigned r = (u + 0x7fffu + ((u >> 16) & 1u)) >> 16;  // RNE
  return (ushort)r;
}
__device__ __forceinline__ float bflo(unsigned p) {  // low bf16 of packed u32
  return __uint_as_float(p << 16);
}
__device__ __forceinline__ float bfhi(unsigned p) {  // high bf16 of packed u32
  return __uint_as_float(p & 0xffff0000u);
}
__device__ __forceinline__ unsigned hipair(unsigned ue, unsigned uo) {
  return (uo & 0xffff0000u) | (ue >> 16);
}

// --- CSR build (unchanged) --------------------------------------------------

__global__ __launch_bounds__(512) void kb_hist(const int* __restrict__ dst,
                                               int* __restrict__ bcnt, int E) {
  __shared__ int h[NBKT];
  for (int i = threadIdx.x; i < NBKT; i += 512) h[i] = 0;
  __syncthreads();
  int base = blockIdx.x * CHUNK;
#pragma unroll 4
  for (int q = 0; q < CHUNK / 512; q++) {
    int e = base + threadIdx.x + q * 512;
    if (e < E) atomicAdd(&h[dst[e] / BKT_W], 1);
  }
  __syncthreads();
  for (int i = threadIdx.x; i < NBKT; i += 512)
    if (h[i]) atomicAdd(&bcnt[i], h[i]);
}

__global__ __launch_bounds__(512) void kb_scan(const int* __restrict__ bcnt,
                                               int* __restrict__ bbase,
                                               int* __restrict__ bcur,
                                               int* __restrict__ row_ptr,
                                               int N, int E) {
  __shared__ int s[NBKT];
  int t = threadIdx.x;
  int v = bcnt[t];
  s[t] = v;
  __syncthreads();
  for (int off = 1; off < NBKT; off <<= 1) {
    int x = (t >= off) ? s[t - off] : 0;
    __syncthreads();
    s[t] += x;
    __syncthreads();
  }
  int ex = s[t] - v;
  bbase[t] = ex;
  bcur[t] = ex;
  if (t == NBKT - 1) bbase[NBKT] = E;
  if (t == 0) row_ptr[N] = E;
}

__global__ __launch_bounds__(512) void kb_scatter(const int* __restrict__ src,
                                                  const int* __restrict__ dst,
                                                  int* __restrict__ bcur,
                                                  int2* __restrict__ pairs, int E) {
  __shared__ int h[NBKT];
  __shared__ int gb[NBKT];
  for (int i = threadIdx.x; i < NBKT; i += 512) h[i] = 0;
  __syncthreads();

  const int base = blockIdx.x * CHUNK;
  const int t = threadIdx.x;
  int rank[CHUNK / 512], bkt[CHUNK / 512], sv[CHUNK / 512], dv[CHUNK / 512];
#pragma unroll
  for (int q = 0; q < CHUNK / 512; q++) {
    int e = base + t + q * 512;
    if (e < E) {
      int d = dst[e];
      int b = d / BKT_W;
      bkt[q] = b;
      sv[q] = src[e];
      dv[q] = d;
      rank[q] = atomicAdd(&h[b], 1);
    } else {
      bkt[q] = -1;
    }
  }
  __syncthreads();
  for (int i = t; i < NBKT; i += 512) {
    int c = h[i];
    gb[i] = c ? atomicAdd(&bcur[i], c) : 0;
  }
  __syncthreads();
#pragma unroll
  for (int q = 0; q < CHUNK / 512; q++) {
    if (bkt[q] >= 0) pairs[(size_t)gb[bkt[q]] + rank[q]] = make_int2(sv[q], dv[q]);
  }
}

__global__ __launch_bounds__(512) void kb_sort(const int* __restrict__ bbase,
                                               const int2* __restrict__ pairs,
                                               int* __restrict__ csr_src,
                                               int* __restrict__ row_ptr,
                                               int N, int E) {
  __shared__ int cnt[256];
  __shared__ int sc[256];
  __shared__ int cur[256];
  __shared__ int stage[CAP];

  const int b = blockIdx.x;
  const int t = threadIdx.x;
  const int lo = bbase[b], hi = bbase[b + 1];
  const int n0 = b * BKT_W;
  int m = hi - lo;
  if (m > CAP) m = CAP;

  if (t < 256) cnt[t] = 0;
  __syncthreads();

  for (int i = t; i < m; i += 512) {
    int2 p = pairs[(size_t)lo + i];
    atomicAdd(&cnt[p.y - n0], 1);
  }
  __syncthreads();

  int v = 0;
  if (t < 256) {
    v = cnt[t];
    sc[t] = v;
  }
  __syncthreads();
  for (int off = 1; off < 256; off <<= 1) {
    int x = 0;
    if (t < 256 && t >= off) x = sc[t - off];
    __syncthreads();
    if (t < 256) sc[t] += x;
    __syncthreads();
  }
  if (t < 256) {
    int ex = sc[t] - v;
    cur[t] = ex;
    int node = n0 + t;
    if (t < BKT_W && node < N) row_ptr[node] = lo + ex;
  }
  __syncthreads();

  for (int i = t; i < m; i += 512) {
    int2 p = pairs[(size_t)lo + i];
    int pos = atomicAdd(&cur[p.y - n0], 1);
    stage[pos] = p.x;
  }
  __syncthreads();

  for (int i = t; i < m; i += 512) csr_src[(size_t)lo + i] = stage[i];
}

__global__ __launch_bounds__(256) void k_dinv(const int* __restrict__ row_ptr,
                                              float* __restrict__ dinv, int N) {
  int i = blockIdx.x * 256 + threadIdx.x;
  if (i < N) dinv[i] = rsqrtf((float)(row_ptr[i + 1] - row_ptr[i]) + 1.0f);
}

// --- W pre-split (unchanged) ------------------------------------------------
__global__ __launch_bounds__(256) void k_wsplit(const float* __restrict__ W,
                                                ushort* __restrict__ whi,
                                                ushort* __restrict__ wlo) {
  const int t = threadIdx.x;
#pragma unroll
  for (int it = 0; it < 16; ++it) {
    int f4 = it * 256 + t;
    int k = f4 >> 5;
    int n4 = (f4 & 31) * 4;
    float4 v = *(const float4*)(W + (size_t)k * 128 + n4);
    float f[4] = {v.x, v.y, v.z, v.w};
#pragma unroll
    for (int q = 0; q < 4; ++q) {
      int n = n4 + q;
      unsigned u = __float_as_uint(f[q]);
      float lf = f[q] - __uint_as_float(u & 0xffff0000u);
      int bo = (n * 256 + k * 2) ^ ((n & 7) << 4);
      *(ushort*)((char*)whi + bo) = (ushort)(u >> 16);
      *(ushort*)((char*)wlo + bo) = (ushort)(__float_as_uint(lf) >> 16);
    }
  }
}

// --- MFMA GEMM: hs[M][128](bf16) = ((X @ W) * dinv[row]) --------------------
__device__ __forceinline__ void cvt_row(const float* __restrict__ p,
                                        bf16x8* hi, bf16x8* lo) {
  float4 v0 = *(const float4*)p;
  float4 v1 = *(const float4*)(p + 4);
  float f[8] = {v0.x, v0.y, v0.z, v0.w, v1.x, v1.y, v1.z, v1.w};
  unsigned hw[4], lw[4];
#pragma unroll
  for (int i = 0; i < 4; ++i) {
    unsigned u0 = __float_as_uint(f[2 * i]);
    unsigned u1 = __float_as_uint(f[2 * i + 1]);
    float l0 = f[2 * i] - __uint_as_float(u0 & 0xffff0000u);
    float l1 = f[2 * i + 1] - __uint_as_float(u1 & 0xffff0000u);
    hw[i] = hipair(u0, u1);
    lw[i] = hipair(__float_as_uint(l0), __float_as_uint(l1));
  }
  uint4 H = make_uint4(hw[0], hw[1], hw[2], hw[3]);
  uint4 L = make_uint4(lw[0], lw[1], lw[2], lw[3]);
  *hi = __builtin_bit_cast(bf16x8, H);
  *lo = __builtin_bit_cast(bf16x8, L);
}

__global__ __launch_bounds__(256) void k_gemm_mfma(const float* __restrict__ X,
                                                   const ushort* __restrict__ whi,
                                                   const ushort* __restrict__ wlo,
                                                   const float* __restrict__ dinv,
                                                   ushort* __restrict__ hs, int M) {
  __shared__ ushort wt_hi[128 * 128];
  __shared__ ushort wt_lo[128 * 128];

  const int t = threadIdx.x;
#pragma unroll
  for (int it = 0; it < 8; ++it) {
    int o = (it * 256 + t) * 8;
    *(uint4*)&wt_hi[o] = *(const uint4*)&whi[o];
    *(uint4*)&wt_lo[o] = *(const uint4*)&wlo[o];
  }
  __syncthreads();

  const int wv = t >> 6;
  const int lane = t & 63;
  const int r0 = blockIdx.x * 128 + wv * 32;
  const int la = lane & 15;
  const int kg = (lane >> 4) * 8;
  const int rowA = min(r0 + la, M - 1);
  const int rowB = min(r0 + 16 + la, M - 1);

  f32x4 acc[2][8];
#pragma unroll
  for (int rs = 0; rs < 2; ++rs)
#pragma unroll
    for (int ct = 0; ct < 8; ++ct) acc[rs][ct] = (f32x4)(0.f);

#pragma unroll
  for (int ks = 0; ks < 4; ++ks) {
    const int koff = ks * 32 + kg;
    bf16x8 ah0, al0, ah1, al1;
    cvt_row(X + (size_t)rowA * 128 + koff, &ah0, &al0);
    cvt_row(X + (size_t)rowB * 128 + koff, &ah1, &al1);
#pragma unroll
    for (int ct = 0; ct < 8; ++ct) {
      const int n = ct * 16 + la;
      const int bo = (n * 256 + koff * 2) ^ ((n & 7) << 4);
      bf16x8 bh = *(const bf16x8*)((const char*)wt_hi + bo);
      bf16x8 bl = *(const bf16x8*)((const char*)wt_lo + bo);
      acc[0][ct] = __builtin_amdgcn_mfma_f32_16x16x32_bf16(ah0, bh, acc[0][ct], 0, 0, 0);
      acc[0][ct] = __builtin_amdgcn_mfma_f32_16x16x32_bf16(ah0, bl, acc[0][ct], 0, 0, 0);
      acc[0][ct] = __builtin_amdgcn_mfma_f32_16x16x32_bf16(al0, bh, acc[0][ct], 0, 0, 0);
      acc[1][ct] = __builtin_amdgcn_mfma_f32_16x16x32_bf16(ah1, bh, acc[1][ct], 0, 0, 0);
      acc[1][ct] = __builtin_amdgcn_mfma_f32_16x16x32_bf16(ah1, bl, acc[1][ct], 0, 0, 0);
      acc[1][ct] = __builtin_amdgcn_mfma_f32_16x16x32_bf16(al1, bh, acc[1][ct], 0, 0, 0);
    }
  }

  // epilogue: C/D col = lane&15, row = (lane>>4)*4 + j; row-major hs
#pragma unroll
  for (int rs = 0; rs < 2; ++rs) {
#pragma unroll
    for (int j = 0; j < 4; ++j) {
      int r = r0 + rs * 16 + (lane >> 4) * 4 + j;
      if (r < M) {
        float sc = dinv[r];
#pragma unroll
        for (int ct = 0; ct < 8; ++ct)
          hs[(size_t)r * 128 + ct * 16 + la] = f2bf(acc[rs][ct][j] * sc);
      }
    }
  }
}

// --- agg: wave per node; lane = uint2 (4ch), 32 lanes cover the 256B row;
//     half-wave (lane>>5) processes edges of one parity -> 2 edges per load.
__global__ __launch_bounds__(256) void k_agg(const int* __restrict__ row_ptr,
                                             const int* __restrict__ csr_src,
                                             const float* __restrict__ dinv,
                                             const ushort* __restrict__ hs,
                                             const float* __restrict__ bias,
                                             float* __restrict__ out, int N) {
  const int node = blockIdx.x * 4 + (threadIdx.x >> 6);
  if (node >= N) return;
  const int lane = threadIdx.x & 63;
  const int half = lane >> 5;  // edge parity handled by this half-wave
  const int cq = lane & 31;    // uint2 index within row (4 channels)
  const uint2* hp = (const uint2*)hs;  // 32 uint2 per row

  const int e0 = row_ptr[node];
  const int e1 = row_ptr[node + 1];

  float a0 = 0.f, a1 = 0.f, a2 = 0.f, a3 = 0.f;
  int e = e0 + half;
  // 4 edges of this parity per iteration (8 edges per wave-iteration)
  for (; e + 6 < e1; e += 8) {
    int s0 = csr_src[e];
    int s1 = csr_src[e + 2];
    int s2 = csr_src[e + 4];
    int s3 = csr_src[e + 6];
    uint2 v0 = hp[(size_t)s0 * 32 + cq];
    uint2 v1 = hp[(size_t)s1 * 32 + cq];
    uint2 v2 = hp[(size_t)s2 * 32 + cq];
    uint2 v3 = hp[(size_t)s3 * 32 + cq];
    a0 += bflo(v0.x) + bflo(v1.x) + bflo(v2.x) + bflo(v3.x);
    a1 += bfhi(v0.x) + bfhi(v1.x) + bfhi(v2.x) + bfhi(v3.x);
    a2 += bflo(v0.y) + bflo(v1.y) + bflo(v2.y) + bflo(v3.y);
    a3 += bfhi(v0.y) + bfhi(v1.y) + bfhi(v2.y) + bfhi(v3.y);
  }
  for (; e < e1; e += 2) {
    int s = csr_src[e];
    uint2 v = hp[(size_t)s * 32 + cq];
    a0 += bflo(v.x);
    a1 += bfhi(v.x);
    a2 += bflo(v.y);
    a3 += bfhi(v.y);
  }
  // combine the two parity halves (lane L <-> L^32 hold the same channels)
  a0 += __shfl_xor(a0, 32);
  a1 += __shfl_xor(a1, 32);
  a2 += __shfl_xor(a2, 32);
  a3 += __shfl_xor(a3, 32);

  if (half == 0) {
    uint2 sv = hp[(size_t)node * 32 + cq];  // self row
    a0 += bflo(sv.x);
    a1 += bfhi(sv.x);
    a2 += bflo(sv.y);
    a3 += bfhi(sv.y);
    float dv = dinv[node];
    float4 bv = ((const float4*)bias)[cq];
    float4 o;
    o.x = fmaxf(fmaf(a0, dv, bv.x), 0.f);
    o.y = fmaxf(fmaf(a1, dv, bv.y), 0.f);
    o.z = fmaxf(fmaf(a2, dv, bv.z), 0.f);
    o.w = fmaxf(fmaf(a3, dv, bv.w), 0.f);
    ((float4*)out)[(size_t)node * 32 + cq] = o;
  }
}

// ---------------------------------------------------------------------------

extern "C" void kernel_launch(void* const* d_in, const int* in_sizes, int n_in,
                              void* d_out, int out_size, void* d_ws, size_t ws_size,
                              hipStream_t stream) {
  const float* x  = (const float*)d_in[0];
  const int*   ei = (const int*)d_in[1];
  const float* W1 = (const float*)d_in[2];
  const float* b1 = (const float*)d_in[3];
  const float* W2 = (const float*)d_in[4];
  const float* b2 = (const float*)d_in[5];
  float* out = (float*)d_out;

  const int N = NN;
  const int E = in_sizes[1] / 2;
  const int* src = ei;
  const int* dst = ei + E;

  char* w = (char*)d_ws;
  auto alloc = [&](size_t bytes) {
    char* p = w;
    w += (bytes + 255) & ~(size_t)255;
    return p;
  };
  float*  dinv    = (float*)alloc((size_t)N * 4);
  int*    row_ptr = (int*)alloc((size_t)(N + 1) * 4);
  int*    bcnt    = (int*)alloc(NBKT * 4);
  int*    bbase   = (int*)alloc((NBKT + 1) * 4);
  int*    bcur    = (int*)alloc(NBKT * 4);
  int*    csr_src = (int*)alloc((size_t)E * 4);
  int2*   pairs   = (int2*)alloc((size_t)E * 8);
  ushort* hs      = (ushort*)alloc((size_t)N * 128 * 2);
  ushort* w1hi    = (ushort*)alloc(128 * 128 * 2);
  ushort* w1lo    = (ushort*)alloc(128 * 128 * 2);
  ushort* w2hi    = (ushort*)alloc(128 * 128 * 2);
  ushort* w2lo    = (ushort*)alloc(128 * 128 * 2);

  const int EB = (E + CHUNK - 1) / CHUNK;

  hipMemsetAsync(bcnt, 0, NBKT * 4, stream);
  kb_hist<<<EB, 512, 0, stream>>>(dst, bcnt, E);
  kb_scan<<<1, 512, 0, stream>>>(bcnt, bbase, bcur, row_ptr, N, E);
  kb_scatter<<<EB, 512, 0, stream>>>(src, dst, bcur, pairs, E);
  kb_sort<<<NBKT, 512, 0, stream>>>(bbase, pairs, csr_src, row_ptr, N, E);
  k_dinv<<<(N + 255) / 256, 256, 0, stream>>>(row_ptr, dinv, N);
  k_wsplit<<<1, 256, 0, stream>>>(W1, w1hi, w1lo);
  k_wsplit<<<1, 256, 0, stream>>>(W2, w2hi, w2lo);

  const int GB = (N + 127) / 128;
  const int AB = (N + 3) / 4;

  // layer 1
  k_gemm_mfma<<<GB, 256, 0, stream>>>(x, w1hi, w1lo, dinv, hs, N);
  k_agg<<<AB, 256, 0, stream>>>(row_ptr, csr_src, dinv, hs, b1, out, N);
  // layer 2
  k_gemm_mfma<<<GB, 256, 0, stream>>>(out, w2hi, w2lo, dinv, hs, N);
  k_agg<<<AB, 256, 0, stream>>>(row_ptr, csr_src, dinv, hs, b2, out, N);
}

// Round 10
// 336.572 us; speedup vs baseline: 1.2104x; 1.0493x over previous
//
#include <hip/hip_runtime.h>

// ---------------------------------------------------------------------------
// GCN 2-layer forward, MI355X.
//   CSR build via bucketed counting sort; dinv fused into kb_sort.
//   k_wsplit2   : both W -> bf16 hi/lo [n][k] XOR-swizzled (one launch)
//   Layer 1: k_gemm_mfma (f32 in, 3-pass split-bf16) -> hs
//            k_agg<BF16OUT=1> -> h1b (bf16 activations)
//   Layer 2: k_gemm_mfma_bf (bf16 in, 2-pass) -> hs
//            k_agg<BF16OUT=0> -> d_out (f32)
//   agg: wave per node; lane = uint4 (8ch), 16 lanes/row, quarter-wave
//        edge parity -> 4 edges in flight per load instruction.
// ---------------------------------------------------------------------------

#define NN 100000
#define NBKT 512
#define BKT_W 196
#define CHUNK 8192
#define CAP 6144

typedef __attribute__((ext_vector_type(8))) short bf16x8;
typedef __attribute__((ext_vector_type(4))) float f32x4;

__device__ __forceinline__ ushort f2bf(float f) {
  unsigned u = __float_as_uint(f);
  unsigned r = (u + 0x7fffu + ((u >> 16) & 1u)) >> 16;  // RNE
  return (ushort)r;
}
__device__ __forceinline__ float bflo(unsigned p) {
  return __uint_as_float(p << 16);
}
__device__ __forceinline__ float bfhi(unsigned p) {
  return __uint_as_float(p & 0xffff0000u);
}
__device__ __forceinline__ unsigned hipair(unsigned ue, unsigned uo) {
  return (uo & 0xffff0000u) | (ue >> 16);
}

// --- CSR build ---------------------------------------------------------------

__global__ __launch_bounds__(512) void kb_hist(const int* __restrict__ dst,
                                               int* __restrict__ bcnt, int E) {
  __shared__ int h[NBKT];
  for (int i = threadIdx.x; i < NBKT; i += 512) h[i] = 0;
  __syncthreads();
  int base = blockIdx.x * CHUNK;
#pragma unroll 4
  for (int q = 0; q < CHUNK / 512; q++) {
    int e = base + threadIdx.x + q * 512;
    if (e < E) atomicAdd(&h[dst[e] / BKT_W], 1);
  }
  __syncthreads();
  for (int i = threadIdx.x; i < NBKT; i += 512)
    if (h[i]) atomicAdd(&bcnt[i], h[i]);
}

__global__ __launch_bounds__(512) void kb_scan(const int* __restrict__ bcnt,
                                               int* __restrict__ bbase,
                                               int* __restrict__ bcur,
                                               int* __restrict__ row_ptr,
                                               int N, int E) {
  __shared__ int s[NBKT];
  int t = threadIdx.x;
  int v = bcnt[t];
  s[t] = v;
  __syncthreads();
  for (int off = 1; off < NBKT; off <<= 1) {
    int x = (t >= off) ? s[t - off] : 0;
    __syncthreads();
    s[t] += x;
    __syncthreads();
  }
  int ex = s[t] - v;
  bbase[t] = ex;
  bcur[t] = ex;
  if (t == NBKT - 1) bbase[NBKT] = E;
  if (t == 0) row_ptr[N] = E;
}

__global__ __launch_bounds__(512) void kb_scatter(const int* __restrict__ src,
                                                  const int* __restrict__ dst,
                                                  int* __restrict__ bcur,
                                                  int2* __restrict__ pairs, int E) {
  __shared__ int h[NBKT];
  __shared__ int gb[NBKT];
  for (int i = threadIdx.x; i < NBKT; i += 512) h[i] = 0;
  __syncthreads();

  const int base = blockIdx.x * CHUNK;
  const int t = threadIdx.x;
  int rank[CHUNK / 512], bkt[CHUNK / 512], sv[CHUNK / 512], dv[CHUNK / 512];
#pragma unroll
  for (int q = 0; q < CHUNK / 512; q++) {
    int e = base + t + q * 512;
    if (e < E) {
      int d = dst[e];
      int b = d / BKT_W;
      bkt[q] = b;
      sv[q] = src[e];
      dv[q] = d;
      rank[q] = atomicAdd(&h[b], 1);
    } else {
      bkt[q] = -1;
    }
  }
  __syncthreads();
  for (int i = t; i < NBKT; i += 512) {
    int c = h[i];
    gb[i] = c ? atomicAdd(&bcur[i], c) : 0;
  }
  __syncthreads();
#pragma unroll
  for (int q = 0; q < CHUNK / 512; q++) {
    if (bkt[q] >= 0) pairs[(size_t)gb[bkt[q]] + rank[q]] = make_int2(sv[q], dv[q]);
  }
}

// per bucket: counting sort in LDS -> csr_src, row_ptr, dinv (fused)
__global__ __launch_bounds__(512) void kb_sort(const int* __restrict__ bbase,
                                               const int2* __restrict__ pairs,
                                               int* __restrict__ csr_src,
                                               int* __restrict__ row_ptr,
                                               float* __restrict__ dinv,
                                               int N, int E) {
  __shared__ int cnt[256];
  __shared__ int sc[256];
  __shared__ int cur[256];
  __shared__ int stage[CAP];

  const int b = blockIdx.x;
  const int t = threadIdx.x;
  const int lo = bbase[b], hi = bbase[b + 1];
  const int n0 = b * BKT_W;
  int m = hi - lo;
  if (m > CAP) m = CAP;

  if (t < 256) cnt[t] = 0;
  __syncthreads();

  for (int i = t; i < m; i += 512) {
    int2 p = pairs[(size_t)lo + i];
    atomicAdd(&cnt[p.y - n0], 1);
  }
  __syncthreads();

  int v = 0;
  if (t < 256) {
    v = cnt[t];
    sc[t] = v;
  }
  __syncthreads();
  for (int off = 1; off < 256; off <<= 1) {
    int x = 0;
    if (t < 256 && t >= off) x = sc[t - off];
    __syncthreads();
    if (t < 256) sc[t] += x;
    __syncthreads();
  }
  if (t < 256) {
    int ex = sc[t] - v;
    cur[t] = ex;
    int node = n0 + t;
    if (t < BKT_W && node < N) {
      row_ptr[node] = lo + ex;
      dinv[node] = rsqrtf((float)v + 1.0f);  // degree = in-edge count
    }
  }
  __syncthreads();

  for (int i = t; i < m; i += 512) {
    int2 p = pairs[(size_t)lo + i];
    int pos = atomicAdd(&cur[p.y - n0], 1);
    stage[pos] = p.x;
  }
  __syncthreads();

  for (int i = t; i < m; i += 512) csr_src[(size_t)lo + i] = stage[i];
}

// --- both W pre-splits in one launch (2 blocks) -----------------------------
__global__ __launch_bounds__(256) void k_wsplit2(const float* __restrict__ W1,
                                                 const float* __restrict__ W2,
                                                 ushort* __restrict__ w1hi,
                                                 ushort* __restrict__ w1lo,
                                                 ushort* __restrict__ w2hi,
                                                 ushort* __restrict__ w2lo) {
  const float* W = blockIdx.x ? W2 : W1;
  ushort* whi = blockIdx.x ? w2hi : w1hi;
  ushort* wlo = blockIdx.x ? w2lo : w1lo;
  const int t = threadIdx.x;
#pragma unroll
  for (int it = 0; it < 16; ++it) {
    int f4 = it * 256 + t;
    int k = f4 >> 5;
    int n4 = (f4 & 31) * 4;
    float4 v = *(const float4*)(W + (size_t)k * 128 + n4);
    float f[4] = {v.x, v.y, v.z, v.w};
#pragma unroll
    for (int q = 0; q < 4; ++q) {
      int n = n4 + q;
      unsigned u = __float_as_uint(f[q]);
      float lf = f[q] - __uint_as_float(u & 0xffff0000u);
      int bo = (n * 256 + k * 2) ^ ((n & 7) << 4);
      *(ushort*)((char*)whi + bo) = (ushort)(u >> 16);
      *(ushort*)((char*)wlo + bo) = (ushort)(__float_as_uint(lf) >> 16);
    }
  }
}

// --- GEMM layer 1: f32 input, 3-pass split-bf16 -----------------------------
__device__ __forceinline__ void cvt_row(const float* __restrict__ p,
                                        bf16x8* hi, bf16x8* lo) {
  float4 v0 = *(const float4*)p;
  float4 v1 = *(const float4*)(p + 4);
  float f[8] = {v0.x, v0.y, v0.z, v0.w, v1.x, v1.y, v1.z, v1.w};
  unsigned hw[4], lw[4];
#pragma unroll
  for (int i = 0; i < 4; ++i) {
    unsigned u0 = __float_as_uint(f[2 * i]);
    unsigned u1 = __float_as_uint(f[2 * i + 1]);
    float l0 = f[2 * i] - __uint_as_float(u0 & 0xffff0000u);
    float l1 = f[2 * i + 1] - __uint_as_float(u1 & 0xffff0000u);
    hw[i] = hipair(u0, u1);
    lw[i] = hipair(__float_as_uint(l0), __float_as_uint(l1));
  }
  uint4 H = make_uint4(hw[0], hw[1], hw[2], hw[3]);
  uint4 L = make_uint4(lw[0], lw[1], lw[2], lw[3]);
  *hi = __builtin_bit_cast(bf16x8, H);
  *lo = __builtin_bit_cast(bf16x8, L);
}

__global__ __launch_bounds__(256) void k_gemm_mfma(const float* __restrict__ X,
                                                   const ushort* __restrict__ whi,
                                                   const ushort* __restrict__ wlo,
                                                   const float* __restrict__ dinv,
                                                   ushort* __restrict__ hs, int M) {
  __shared__ ushort wt_hi[128 * 128];
  __shared__ ushort wt_lo[128 * 128];

  const int t = threadIdx.x;
#pragma unroll
  for (int it = 0; it < 8; ++it) {
    int o = (it * 256 + t) * 8;
    *(uint4*)&wt_hi[o] = *(const uint4*)&whi[o];
    *(uint4*)&wt_lo[o] = *(const uint4*)&wlo[o];
  }
  __syncthreads();

  const int wv = t >> 6;
  const int lane = t & 63;
  const int r0 = blockIdx.x * 128 + wv * 32;
  const int la = lane & 15;
  const int kg = (lane >> 4) * 8;
  const int rowA = min(r0 + la, M - 1);
  const int rowB = min(r0 + 16 + la, M - 1);

  f32x4 acc[2][8];
#pragma unroll
  for (int rs = 0; rs < 2; ++rs)
#pragma unroll
    for (int ct = 0; ct < 8; ++ct) acc[rs][ct] = (f32x4)(0.f);

#pragma unroll
  for (int ks = 0; ks < 4; ++ks) {
    const int koff = ks * 32 + kg;
    bf16x8 ah0, al0, ah1, al1;
    cvt_row(X + (size_t)rowA * 128 + koff, &ah0, &al0);
    cvt_row(X + (size_t)rowB * 128 + koff, &ah1, &al1);
#pragma unroll
    for (int ct = 0; ct < 8; ++ct) {
      const int n = ct * 16 + la;
      const int bo = (n * 256 + koff * 2) ^ ((n & 7) << 4);
      bf16x8 bh = *(const bf16x8*)((const char*)wt_hi + bo);
      bf16x8 bl = *(const bf16x8*)((const char*)wt_lo + bo);
      acc[0][ct] = __builtin_amdgcn_mfma_f32_16x16x32_bf16(ah0, bh, acc[0][ct], 0, 0, 0);
      acc[0][ct] = __builtin_amdgcn_mfma_f32_16x16x32_bf16(ah0, bl, acc[0][ct], 0, 0, 0);
      acc[0][ct] = __builtin_amdgcn_mfma_f32_16x16x32_bf16(al0, bh, acc[0][ct], 0, 0, 0);
      acc[1][ct] = __builtin_amdgcn_mfma_f32_16x16x32_bf16(ah1, bh, acc[1][ct], 0, 0, 0);
      acc[1][ct] = __builtin_amdgcn_mfma_f32_16x16x32_bf16(ah1, bl, acc[1][ct], 0, 0, 0);
      acc[1][ct] = __builtin_amdgcn_mfma_f32_16x16x32_bf16(al1, bh, acc[1][ct], 0, 0, 0);
    }
  }

#pragma unroll
  for (int rs = 0; rs < 2; ++rs) {
#pragma unroll
    for (int j = 0; j < 4; ++j) {
      int r = r0 + rs * 16 + (lane >> 4) * 4 + j;
      if (r < M) {
        float sc = dinv[r];
#pragma unroll
        for (int ct = 0; ct < 8; ++ct)
          hs[(size_t)r * 128 + ct * 16 + la] = f2bf(acc[rs][ct][j] * sc);
      }
    }
  }
}

// --- GEMM layer 2: bf16 input (exact), 2-pass -------------------------------
__global__ __launch_bounds__(256) void k_gemm_mfma_bf(const ushort* __restrict__ Xb,
                                                      const ushort* __restrict__ whi,
                                                      const ushort* __restrict__ wlo,
                                                      const float* __restrict__ dinv,
                                                      ushort* __restrict__ hs, int M) {
  __shared__ ushort wt_hi[128 * 128];
  __shared__ ushort wt_lo[128 * 128];

  const int t = threadIdx.x;
#pragma unroll
  for (int it = 0; it < 8; ++it) {
    int o = (it * 256 + t) * 8;
    *(uint4*)&wt_hi[o] = *(const uint4*)&whi[o];
    *(uint4*)&wt_lo[o] = *(const uint4*)&wlo[o];
  }
  __syncthreads();

  const int wv = t >> 6;
  const int lane = t & 63;
  const int r0 = blockIdx.x * 128 + wv * 32;
  const int la = lane & 15;
  const int kg = (lane >> 4) * 8;
  const int rowA = min(r0 + la, M - 1);
  const int rowB = min(r0 + 16 + la, M - 1);

  f32x4 acc[2][8];
#pragma unroll
  for (int rs = 0; rs < 2; ++rs)
#pragma unroll
    for (int ct = 0; ct < 8; ++ct) acc[rs][ct] = (f32x4)(0.f);

#pragma unroll
  for (int ks = 0; ks < 4; ++ks) {
    const int koff = ks * 32 + kg;
    bf16x8 a0 = *(const bf16x8*)(Xb + (size_t)rowA * 128 + koff);
    bf16x8 a1 = *(const bf16x8*)(Xb + (size_t)rowB * 128 + koff);
#pragma unroll
    for (int ct = 0; ct < 8; ++ct) {
      const int n = ct * 16 + la;
      const int bo = (n * 256 + koff * 2) ^ ((n & 7) << 4);
      bf16x8 bh = *(const bf16x8*)((const char*)wt_hi + bo);
      bf16x8 bl = *(const bf16x8*)((const char*)wt_lo + bo);
      acc[0][ct] = __builtin_amdgcn_mfma_f32_16x16x32_bf16(a0, bh, acc[0][ct], 0, 0, 0);
      acc[0][ct] = __builtin_amdgcn_mfma_f32_16x16x32_bf16(a0, bl, acc[0][ct], 0, 0, 0);
      acc[1][ct] = __builtin_amdgcn_mfma_f32_16x16x32_bf16(a1, bh, acc[1][ct], 0, 0, 0);
      acc[1][ct] = __builtin_amdgcn_mfma_f32_16x16x32_bf16(a1, bl, acc[1][ct], 0, 0, 0);
    }
  }

#pragma unroll
  for (int rs = 0; rs < 2; ++rs) {
#pragma unroll
    for (int j = 0; j < 4; ++j) {
      int r = r0 + rs * 16 + (lane >> 4) * 4 + j;
      if (r < M) {
        float sc = dinv[r];
#pragma unroll
        for (int ct = 0; ct < 8; ++ct)
          hs[(size_t)r * 128 + ct * 16 + la] = f2bf(acc[rs][ct][j] * sc);
      }
    }
  }
}

// --- agg: wave/node; lane = uint4 (8ch), 16 lanes/row, quarter-wave parity --
template <int BF16OUT>
__global__ __launch_bounds__(256) void k_agg(const int* __restrict__ row_ptr,
                                             const int* __restrict__ csr_src,
                                             const float* __restrict__ dinv,
                                             const ushort* __restrict__ hs,
                                             const float* __restrict__ bias,
                                             void* __restrict__ outv, int N) {
  const int node = blockIdx.x * 4 + (threadIdx.x >> 6);
  if (node >= N) return;
  const int lane = threadIdx.x & 63;
  const int qg = lane >> 4;  // edge parity 0..3
  const int cx = lane & 15;  // uint4 index within 128-ch row
  const uint4* hp = (const uint4*)hs;  // 16 uint4 per row

  const int e0 = row_ptr[node];
  const int e1 = row_ptr[node + 1];

  float a[8];
#pragma unroll
  for (int i = 0; i < 8; ++i) a[i] = 0.f;

  int e = e0 + qg;
  for (; e + 4 < e1; e += 8) {  // 2 edges/group-iter = 8 edges/wave-iter
    int s0 = csr_src[e];
    int s1 = csr_src[e + 4];
    uint4 v0 = hp[(size_t)s0 * 16 + cx];
    uint4 v1 = hp[(size_t)s1 * 16 + cx];
    a[0] += bflo(v0.x) + bflo(v1.x);
    a[1] += bfhi(v0.x) + bfhi(v1.x);
    a[2] += bflo(v0.y) + bflo(v1.y);
    a[3] += bfhi(v0.y) + bfhi(v1.y);
    a[4] += bflo(v0.z) + bflo(v1.z);
    a[5] += bfhi(v0.z) + bfhi(v1.z);
    a[6] += bflo(v0.w) + bflo(v1.w);
    a[7] += bfhi(v0.w) + bfhi(v1.w);
  }
  for (; e < e1; e += 4) {
    int s = csr_src[e];
    uint4 v = hp[(size_t)s * 16 + cx];
    a[0] += bflo(v.x);
    a[1] += bfhi(v.x);
    a[2] += bflo(v.y);
    a[3] += bfhi(v.y);
    a[4] += bflo(v.z);
    a[5] += bfhi(v.z);
    a[6] += bflo(v.w);
    a[7] += bfhi(v.w);
  }
  // merge 4 parity groups: lanes l, l^16, l^32, l^48 share channel set cx
#pragma unroll
  for (int i = 0; i < 8; ++i) {
    a[i] += __shfl_xor(a[i], 16);
    a[i] += __shfl_xor(a[i], 32);
  }

  if (qg == 0) {
    uint4 sv = hp[(size_t)node * 16 + cx];  // self row
    a[0] += bflo(sv.x);
    a[1] += bfhi(sv.x);
    a[2] += bflo(sv.y);
    a[3] += bfhi(sv.y);
    a[4] += bflo(sv.z);
    a[5] += bfhi(sv.z);
    a[6] += bflo(sv.w);
    a[7] += bfhi(sv.w);
    float dv = dinv[node];
    float4 b0 = ((const float4*)bias)[cx * 2];
    float4 b1 = ((const float4*)bias)[cx * 2 + 1];
    float o[8];
    o[0] = fmaxf(fmaf(a[0], dv, b0.x), 0.f);
    o[1] = fmaxf(fmaf(a[1], dv, b0.y), 0.f);
    o[2] = fmaxf(fmaf(a[2], dv, b0.z), 0.f);
    o[3] = fmaxf(fmaf(a[3], dv, b0.w), 0.f);
    o[4] = fmaxf(fmaf(a[4], dv, b1.x), 0.f);
    o[5] = fmaxf(fmaf(a[5], dv, b1.y), 0.f);
    o[6] = fmaxf(fmaf(a[6], dv, b1.z), 0.f);
    o[7] = fmaxf(fmaf(a[7], dv, b1.w), 0.f);
    if (BF16OUT) {
      ushort u[8];
#pragma unroll
      for (int i = 0; i < 8; ++i) u[i] = f2bf(o[i]);
      ((uint4*)outv)[(size_t)node * 16 + cx] = *(const uint4*)u;
    } else {
      float4* op = (float4*)outv;
      op[(size_t)node * 32 + cx * 2] = make_float4(o[0], o[1], o[2], o[3]);
      op[(size_t)node * 32 + cx * 2 + 1] = make_float4(o[4], o[5], o[6], o[7]);
    }
  }
}

// ---------------------------------------------------------------------------

extern "C" void kernel_launch(void* const* d_in, const int* in_sizes, int n_in,
                              void* d_out, int out_size, void* d_ws, size_t ws_size,
                              hipStream_t stream) {
  const float* x  = (const float*)d_in[0];
  const int*   ei = (const int*)d_in[1];
  const float* W1 = (const float*)d_in[2];
  const float* b1 = (const float*)d_in[3];
  const float* W2 = (const float*)d_in[4];
  const float* b2 = (const float*)d_in[5];
  float* out = (float*)d_out;

  const int N = NN;
  const int E = in_sizes[1] / 2;
  const int* src = ei;
  const int* dst = ei + E;

  char* w = (char*)d_ws;
  auto alloc = [&](size_t bytes) {
    char* p = w;
    w += (bytes + 255) & ~(size_t)255;
    return p;
  };
  float*  dinv    = (float*)alloc((size_t)N * 4);
  int*    row_ptr = (int*)alloc((size_t)(N + 1) * 4);
  int*    bcnt    = (int*)alloc(NBKT * 4);
  int*    bbase   = (int*)alloc((NBKT + 1) * 4);
  int*    bcur    = (int*)alloc(NBKT * 4);
  int*    csr_src = (int*)alloc((size_t)E * 4);
  int2*   pairs   = (int2*)alloc((size_t)E * 8);
  ushort* hs      = (ushort*)alloc((size_t)N * 128 * 2);
  ushort* h1b     = (ushort*)alloc((size_t)N * 128 * 2);  // bf16 layer-1 acts
  ushort* w1hi    = (ushort*)alloc(128 * 128 * 2);
  ushort* w1lo    = (ushort*)alloc(128 * 128 * 2);
  ushort* w2hi    = (ushort*)alloc(128 * 128 * 2);
  ushort* w2lo    = (ushort*)alloc(128 * 128 * 2);

  const int EB = (E + CHUNK - 1) / CHUNK;

  hipMemsetAsync(bcnt, 0, NBKT * 4, stream);
  kb_hist<<<EB, 512, 0, stream>>>(dst, bcnt, E);
  kb_scan<<<1, 512, 0, stream>>>(bcnt, bbase, bcur, row_ptr, N, E);
  kb_scatter<<<EB, 512, 0, stream>>>(src, dst, bcur, pairs, E);
  kb_sort<<<NBKT, 512, 0, stream>>>(bbase, pairs, csr_src, row_ptr, dinv, N, E);
  k_wsplit2<<<2, 256, 0, stream>>>(W1, W2, w1hi, w1lo, w2hi, w2lo);

  const int GB = (N + 127) / 128;
  const int AB = (N + 3) / 4;

  // layer 1
  k_gemm_mfma<<<GB, 256, 0, stream>>>(x, w1hi, w1lo, dinv, hs, N);
  k_agg<1><<<AB, 256, 0, stream>>>(row_ptr, csr_src, dinv, hs, b1, h1b, N);
  // layer 2
  k_gemm_mfma_bf<<<GB, 256, 0, stream>>>(h1b, w2hi, w2lo, dinv, hs, N);
  k_agg<0><<<AB, 256, 0, stream>>>(row_ptr, csr_src, dinv, hs, b2, out, N);
}

// Round 11
// 316.359 us; speedup vs baseline: 1.2878x; 1.0639x over previous
//
#include <hip/hip_runtime.h>

// ---------------------------------------------------------------------------
// GCN 2-layer forward, MI355X.
//   CSR build via bucketed counting sort (pairs packed u32: ldst<<24|src);
//   dinv fused into kb_sort; W-split fused into kb_hist's launch.
//   Layer 1: k_gemm<1> (f32 in, truncate->bf16, 2-pass vs exact-split W) -> hs
//            k_agg<1> -> h1b (bf16)
//   Layer 2: k_gemm<0> (bf16 in, 2-pass) -> hs
//            k_agg<0> -> d_out (f32)
//   agg: wave/node, lane=uint4(8ch), 16 lanes/row, quarter-wave edge parity.
//   NOTE (r9/r10 evidence): agg is pinned at ~3.55TB/s L2-miss-path BW
//   (FETCH=192MB = 25.6MB hs x ~7.2 XCD duplication, random graph) — further
//   issue-cost cuts were measured neutral; do not touch.
// ---------------------------------------------------------------------------

#define NN 100000
#define NBKT 512
#define BKT_W 196
#define CHUNK 8192
#define CAP 6144

typedef __attribute__((ext_vector_type(8))) short bf16x8;
typedef __attribute__((ext_vector_type(4))) float f32x4;

__device__ __forceinline__ ushort f2bf(float f) {
  unsigned u = __float_as_uint(f);
  unsigned r = (u + 0x7fffu + ((u >> 16) & 1u)) >> 16;  // RNE
  return (ushort)r;
}
__device__ __forceinline__ float bflo(unsigned p) {
  return __uint_as_float(p << 16);
}
__device__ __forceinline__ float bfhi(unsigned p) {
  return __uint_as_float(p & 0xffff0000u);
}
__device__ __forceinline__ unsigned hipair(unsigned ue, unsigned uo) {
  return (uo & 0xffff0000u) | (ue >> 16);
}

// --- CSR build ---------------------------------------------------------------

// blocks [0,EB): bucket histogram; blocks EB,EB+1: W1/W2 hi/lo split.
__global__ __launch_bounds__(512) void kb_hist_wsplit(
    const int* __restrict__ dst, int* __restrict__ bcnt, int E, int EB,
    const float* __restrict__ W1, const float* __restrict__ W2,
    ushort* __restrict__ w1hi, ushort* __restrict__ w1lo,
    ushort* __restrict__ w2hi, ushort* __restrict__ w2lo) {
  const int t = threadIdx.x;
  if ((int)blockIdx.x >= EB) {
    const int wsel = blockIdx.x - EB;
    const float* W = wsel ? W2 : W1;
    ushort* whi = wsel ? w2hi : w1hi;
    ushort* wlo = wsel ? w2lo : w1lo;
#pragma unroll
    for (int it = 0; it < 8; ++it) {
      int f4 = it * 512 + t;  // 0..4095
      int k = f4 >> 5;
      int n4 = (f4 & 31) * 4;
      float4 v = *(const float4*)(W + (size_t)k * 128 + n4);
      float f[4] = {v.x, v.y, v.z, v.w};
#pragma unroll
      for (int q = 0; q < 4; ++q) {
        int n = n4 + q;
        unsigned u = __float_as_uint(f[q]);
        float lf = f[q] - __uint_as_float(u & 0xffff0000u);  // exact residual
        int bo = (n * 256 + k * 2) ^ ((n & 7) << 4);
        *(ushort*)((char*)whi + bo) = (ushort)(u >> 16);
        *(ushort*)((char*)wlo + bo) = (ushort)(__float_as_uint(lf) >> 16);
      }
    }
    return;
  }
  __shared__ int h[NBKT];
  for (int i = t; i < NBKT; i += 512) h[i] = 0;
  __syncthreads();
  int base = blockIdx.x * CHUNK;
#pragma unroll 4
  for (int q = 0; q < CHUNK / 512; q++) {
    int e = base + t + q * 512;
    if (e < E) atomicAdd(&h[dst[e] / BKT_W], 1);
  }
  __syncthreads();
  for (int i = t; i < NBKT; i += 512)
    if (h[i]) atomicAdd(&bcnt[i], h[i]);
}

__global__ __launch_bounds__(512) void kb_scan(const int* __restrict__ bcnt,
                                               int* __restrict__ bbase,
                                               int* __restrict__ bcur,
                                               int* __restrict__ row_ptr,
                                               int N, int E) {
  __shared__ int s[NBKT];
  int t = threadIdx.x;
  int v = bcnt[t];
  s[t] = v;
  __syncthreads();
  for (int off = 1; off < NBKT; off <<= 1) {
    int x = (t >= off) ? s[t - off] : 0;
    __syncthreads();
    s[t] += x;
    __syncthreads();
  }
  int ex = s[t] - v;
  bbase[t] = ex;
  bcur[t] = ex;
  if (t == NBKT - 1) bbase[NBKT] = E;
  if (t == 0) row_ptr[N] = E;
}

// packed pair: (dst - bucket_base) << 24 | src   (src < 2^17, local < 196)
__global__ __launch_bounds__(512) void kb_scatter(const int* __restrict__ src,
                                                  const int* __restrict__ dst,
                                                  int* __restrict__ bcur,
                                                  unsigned* __restrict__ pairs, int E) {
  __shared__ int h[NBKT];
  __shared__ int gb[NBKT];
  for (int i = threadIdx.x; i < NBKT; i += 512) h[i] = 0;
  __syncthreads();

  const int base = blockIdx.x * CHUNK;
  const int t = threadIdx.x;
  int rank[CHUNK / 512], bkt[CHUNK / 512];
  unsigned pv[CHUNK / 512];
#pragma unroll
  for (int q = 0; q < CHUNK / 512; q++) {
    int e = base + t + q * 512;
    if (e < E) {
      int d = dst[e];
      int b = d / BKT_W;
      bkt[q] = b;
      pv[q] = ((unsigned)(d - b * BKT_W) << 24) | (unsigned)src[e];
      rank[q] = atomicAdd(&h[b], 1);
    } else {
      bkt[q] = -1;
    }
  }
  __syncthreads();
  for (int i = t; i < NBKT; i += 512) {
    int c = h[i];
    gb[i] = c ? atomicAdd(&bcur[i], c) : 0;
  }
  __syncthreads();
#pragma unroll
  for (int q = 0; q < CHUNK / 512; q++) {
    if (bkt[q] >= 0) pairs[(size_t)gb[bkt[q]] + rank[q]] = pv[q];
  }
}

// per bucket: counting sort in LDS -> csr_src, row_ptr, dinv
__global__ __launch_bounds__(512) void kb_sort(const int* __restrict__ bbase,
                                               const unsigned* __restrict__ pairs,
                                               int* __restrict__ csr_src,
                                               int* __restrict__ row_ptr,
                                               float* __restrict__ dinv,
                                               int N, int E) {
  __shared__ int cnt[256];
  __shared__ int sc[256];
  __shared__ int cur[256];
  __shared__ int stage[CAP];

  const int b = blockIdx.x;
  const int t = threadIdx.x;
  const int lo = bbase[b], hi = bbase[b + 1];
  const int n0 = b * BKT_W;
  int m = hi - lo;
  if (m > CAP) m = CAP;

  if (t < 256) cnt[t] = 0;
  __syncthreads();

  for (int i = t; i < m; i += 512) {
    unsigned p = pairs[(size_t)lo + i];
    atomicAdd(&cnt[p >> 24], 1);
  }
  __syncthreads();

  int v = 0;
  if (t < 256) {
    v = cnt[t];
    sc[t] = v;
  }
  __syncthreads();
  for (int off = 1; off < 256; off <<= 1) {
    int x = 0;
    if (t < 256 && t >= off) x = sc[t - off];
    __syncthreads();
    if (t < 256) sc[t] += x;
    __syncthreads();
  }
  if (t < 256) {
    int ex = sc[t] - v;
    cur[t] = ex;
    int node = n0 + t;
    if (t < BKT_W && node < N) {
      row_ptr[node] = lo + ex;
      dinv[node] = rsqrtf((float)v + 1.0f);
    }
  }
  __syncthreads();

  for (int i = t; i < m; i += 512) {
    unsigned p = pairs[(size_t)lo + i];
    int pos = atomicAdd(&cur[p >> 24], 1);
    stage[pos] = (int)(p & 0xFFFFFFu);
  }
  __syncthreads();

  for (int i = t; i < m; i += 512) csr_src[(size_t)lo + i] = stage[i];
}

// --- GEMM (both layers): hs[M][128](bf16) = ((X @ W) * dinv[row]) -----------
// F32IN=1: X f32, truncated to bf16 in-register (2-pass: A*Wh + A*Wl).
// F32IN=0: X bf16 exact (2-pass). W exact as hi+lo (split err ~2^-17).
template <int F32IN>
__global__ __launch_bounds__(256) void k_gemm(const void* __restrict__ Xv,
                                              const ushort* __restrict__ whi,
                                              const ushort* __restrict__ wlo,
                                              const float* __restrict__ dinv,
                                              ushort* __restrict__ hs, int M) {
  __shared__ ushort wt_hi[128 * 128];
  __shared__ ushort wt_lo[128 * 128];

  const int t = threadIdx.x;
#pragma unroll
  for (int it = 0; it < 8; ++it) {
    int o = (it * 256 + t) * 8;
    *(uint4*)&wt_hi[o] = *(const uint4*)&whi[o];
    *(uint4*)&wt_lo[o] = *(const uint4*)&wlo[o];
  }
  __syncthreads();

  const int wv = t >> 6;
  const int lane = t & 63;
  const int r0 = blockIdx.x * 128 + wv * 32;
  const int la = lane & 15;
  const int kg = (lane >> 4) * 8;
  const int rowA = min(r0 + la, M - 1);
  const int rowB = min(r0 + 16 + la, M - 1);

  f32x4 acc[2][8];
#pragma unroll
  for (int rs = 0; rs < 2; ++rs)
#pragma unroll
    for (int ct = 0; ct < 8; ++ct) acc[rs][ct] = (f32x4)(0.f);

#pragma unroll
  for (int ks = 0; ks < 4; ++ks) {
    const int koff = ks * 32 + kg;
    bf16x8 a0, a1;
    if (F32IN) {
      const float* pA = (const float*)Xv + (size_t)rowA * 128 + koff;
      const float* pB = (const float*)Xv + (size_t)rowB * 128 + koff;
      float4 u0 = *(const float4*)pA, u1 = *(const float4*)(pA + 4);
      float4 v0 = *(const float4*)pB, v1 = *(const float4*)(pB + 4);
      uint4 H0 = make_uint4(
          hipair(__float_as_uint(u0.x), __float_as_uint(u0.y)),
          hipair(__float_as_uint(u0.z), __float_as_uint(u0.w)),
          hipair(__float_as_uint(u1.x), __float_as_uint(u1.y)),
          hipair(__float_as_uint(u1.z), __float_as_uint(u1.w)));
      uint4 H1 = make_uint4(
          hipair(__float_as_uint(v0.x), __float_as_uint(v0.y)),
          hipair(__float_as_uint(v0.z), __float_as_uint(v0.w)),
          hipair(__float_as_uint(v1.x), __float_as_uint(v1.y)),
          hipair(__float_as_uint(v1.z), __float_as_uint(v1.w)));
      a0 = __builtin_bit_cast(bf16x8, H0);
      a1 = __builtin_bit_cast(bf16x8, H1);
    } else {
      a0 = *(const bf16x8*)((const ushort*)Xv + (size_t)rowA * 128 + koff);
      a1 = *(const bf16x8*)((const ushort*)Xv + (size_t)rowB * 128 + koff);
    }
#pragma unroll
    for (int ct = 0; ct < 8; ++ct) {
      const int n = ct * 16 + la;
      const int bo = (n * 256 + koff * 2) ^ ((n & 7) << 4);
      bf16x8 bh = *(const bf16x8*)((const char*)wt_hi + bo);
      bf16x8 bl = *(const bf16x8*)((const char*)wt_lo + bo);
      acc[0][ct] = __builtin_amdgcn_mfma_f32_16x16x32_bf16(a0, bh, acc[0][ct], 0, 0, 0);
      acc[0][ct] = __builtin_amdgcn_mfma_f32_16x16x32_bf16(a0, bl, acc[0][ct], 0, 0, 0);
      acc[1][ct] = __builtin_amdgcn_mfma_f32_16x16x32_bf16(a1, bh, acc[1][ct], 0, 0, 0);
      acc[1][ct] = __builtin_amdgcn_mfma_f32_16x16x32_bf16(a1, bl, acc[1][ct], 0, 0, 0);
    }
  }

#pragma unroll
  for (int rs = 0; rs < 2; ++rs) {
#pragma unroll
    for (int j = 0; j < 4; ++j) {
      int r = r0 + rs * 16 + (lane >> 4) * 4 + j;
      if (r < M) {
        float sc = dinv[r];
#pragma unroll
        for (int ct = 0; ct < 8; ++ct)
          hs[(size_t)r * 128 + ct * 16 + la] = f2bf(acc[rs][ct][j] * sc);
      }
    }
  }
}

// --- agg (closed at BW ceiling; unchanged from r10) -------------------------
template <int BF16OUT>
__global__ __launch_bounds__(256) void k_agg(const int* __restrict__ row_ptr,
                                             const int* __restrict__ csr_src,
                                             const float* __restrict__ dinv,
                                             const ushort* __restrict__ hs,
                                             const float* __restrict__ bias,
                                             void* __restrict__ outv, int N) {
  const int node = blockIdx.x * 4 + (threadIdx.x >> 6);
  if (node >= N) return;
  const int lane = threadIdx.x & 63;
  const int qg = lane >> 4;
  const int cx = lane & 15;
  const uint4* hp = (const uint4*)hs;

  const int e0 = row_ptr[node];
  const int e1 = row_ptr[node + 1];

  float a[8];
#pragma unroll
  for (int i = 0; i < 8; ++i) a[i] = 0.f;

  int e = e0 + qg;
  for (; e + 4 < e1; e += 8) {
    int s0 = csr_src[e];
    int s1 = csr_src[e + 4];
    uint4 v0 = hp[(size_t)s0 * 16 + cx];
    uint4 v1 = hp[(size_t)s1 * 16 + cx];
    a[0] += bflo(v0.x) + bflo(v1.x);
    a[1] += bfhi(v0.x) + bfhi(v1.x);
    a[2] += bflo(v0.y) + bflo(v1.y);
    a[3] += bfhi(v0.y) + bfhi(v1.y);
    a[4] += bflo(v0.z) + bflo(v1.z);
    a[5] += bfhi(v0.z) + bfhi(v1.z);
    a[6] += bflo(v0.w) + bflo(v1.w);
    a[7] += bfhi(v0.w) + bfhi(v1.w);
  }
  for (; e < e1; e += 4) {
    int s = csr_src[e];
    uint4 v = hp[(size_t)s * 16 + cx];
    a[0] += bflo(v.x);
    a[1] += bfhi(v.x);
    a[2] += bflo(v.y);
    a[3] += bfhi(v.y);
    a[4] += bflo(v.z);
    a[5] += bfhi(v.z);
    a[6] += bflo(v.w);
    a[7] += bfhi(v.w);
  }
#pragma unroll
  for (int i = 0; i < 8; ++i) {
    a[i] += __shfl_xor(a[i], 16);
    a[i] += __shfl_xor(a[i], 32);
  }

  if (qg == 0) {
    uint4 sv = hp[(size_t)node * 16 + cx];
    a[0] += bflo(sv.x);
    a[1] += bfhi(sv.x);
    a[2] += bflo(sv.y);
    a[3] += bfhi(sv.y);
    a[4] += bflo(sv.z);
    a[5] += bfhi(sv.z);
    a[6] += bflo(sv.w);
    a[7] += bfhi(sv.w);
    float dv = dinv[node];
    float4 b0 = ((const float4*)bias)[cx * 2];
    float4 b1 = ((const float4*)bias)[cx * 2 + 1];
    float o[8];
    o[0] = fmaxf(fmaf(a[0], dv, b0.x), 0.f);
    o[1] = fmaxf(fmaf(a[1], dv, b0.y), 0.f);
    o[2] = fmaxf(fmaf(a[2], dv, b0.z), 0.f);
    o[3] = fmaxf(fmaf(a[3], dv, b0.w), 0.f);
    o[4] = fmaxf(fmaf(a[4], dv, b1.x), 0.f);
    o[5] = fmaxf(fmaf(a[5], dv, b1.y), 0.f);
    o[6] = fmaxf(fmaf(a[6], dv, b1.z), 0.f);
    o[7] = fmaxf(fmaf(a[7], dv, b1.w), 0.f);
    if (BF16OUT) {
      ushort u[8];
#pragma unroll
      for (int i = 0; i < 8; ++i) u[i] = f2bf(o[i]);
      ((uint4*)outv)[(size_t)node * 16 + cx] = *(const uint4*)u;
    } else {
      float4* op = (float4*)outv;
      op[(size_t)node * 32 + cx * 2] = make_float4(o[0], o[1], o[2], o[3]);
      op[(size_t)node * 32 + cx * 2 + 1] = make_float4(o[4], o[5], o[6], o[7]);
    }
  }
}

// ---------------------------------------------------------------------------

extern "C" void kernel_launch(void* const* d_in, const int* in_sizes, int n_in,
                              void* d_out, int out_size, void* d_ws, size_t ws_size,
                              hipStream_t stream) {
  const float* x  = (const float*)d_in[0];
  const int*   ei = (const int*)d_in[1];
  const float* W1 = (const float*)d_in[2];
  const float* b1 = (const float*)d_in[3];
  const float* W2 = (const float*)d_in[4];
  const float* b2 = (const float*)d_in[5];
  float* out = (float*)d_out;

  const int N = NN;
  const int E = in_sizes[1] / 2;
  const int* src = ei;
  const int* dst = ei + E;

  char* w = (char*)d_ws;
  auto alloc = [&](size_t bytes) {
    char* p = w;
    w += (bytes + 255) & ~(size_t)255;
    return p;
  };
  float*    dinv    = (float*)alloc((size_t)N * 4);
  int*      row_ptr = (int*)alloc((size_t)(N + 1) * 4);
  int*      bcnt    = (int*)alloc(NBKT * 4);
  int*      bbase   = (int*)alloc((NBKT + 1) * 4);
  int*      bcur    = (int*)alloc(NBKT * 4);
  int*      csr_src = (int*)alloc((size_t)E * 4);
  unsigned* pairs   = (unsigned*)alloc((size_t)E * 4);
  ushort*   hs      = (ushort*)alloc((size_t)N * 128 * 2);
  ushort*   h1b     = (ushort*)alloc((size_t)N * 128 * 2);
  ushort*   w1hi    = (ushort*)alloc(128 * 128 * 2);
  ushort*   w1lo    = (ushort*)alloc(128 * 128 * 2);
  ushort*   w2hi    = (ushort*)alloc(128 * 128 * 2);
  ushort*   w2lo    = (ushort*)alloc(128 * 128 * 2);

  const int EB = (E + CHUNK - 1) / CHUNK;  // 196

  hipMemsetAsync(bcnt, 0, NBKT * 4, stream);
  kb_hist_wsplit<<<EB + 2, 512, 0, stream>>>(dst, bcnt, E, EB, W1, W2,
                                             w1hi, w1lo, w2hi, w2lo);
  kb_scan<<<1, 512, 0, stream>>>(bcnt, bbase, bcur, row_ptr, N, E);
  kb_scatter<<<EB, 512, 0, stream>>>(src, dst, bcur, pairs, E);
  kb_sort<<<NBKT, 512, 0, stream>>>(bbase, pairs, csr_src, row_ptr, dinv, N, E);

  const int GB = (N + 127) / 128;
  const int AB = (N + 3) / 4;

  // layer 1
  k_gemm<1><<<GB, 256, 0, stream>>>(x, w1hi, w1lo, dinv, hs, N);
  k_agg<1><<<AB, 256, 0, stream>>>(row_ptr, csr_src, dinv, hs, b1, h1b, N);
  // layer 2
  k_gemm<0><<<GB, 256, 0, stream>>>(h1b, w2hi, w2lo, dinv, hs, N);
  k_agg<0><<<AB, 256, 0, stream>>>(row_ptr, csr_src, dinv, hs, b2, out, N);
}